// Round 7
// baseline (344.422 us; speedup 1.0000x reference)
//
#include <hip/hip_runtime.h>

typedef unsigned long long u64;
typedef unsigned int u32;
typedef unsigned short u16;

#define BATCH 2048
#define DIM   64
#define QSIZE 131072
#define HALFB 1024

#define XCP (BATCH * DIM * 2)      // 256 KB: bytes per x bf16 plane (hi / lo)
#define NBLK 2048                  // sim blocks; 4 waves each; wave = 32 q-cols x 1024 x-rows
#define MROWS 1024                 // x-rows per wave (half of BATCH)
#define WS_SLOTS 16384             // 2048 u64 argmax slots
#define WS_XC    (2 * XCP)         // 512 KB bf16 planes
#define WS_CAND  ((size_t)NBLK * MROWS * 8)   // 16 MB candidate buffer
#define WS_NEED  (WS_SLOTS + WS_XC + WS_CAND)

typedef __attribute__((ext_vector_type(8)))  short short8;
typedef __attribute__((ext_vector_type(4)))  short short4v;
typedef __attribute__((ext_vector_type(16))) float f32x16;

__device__ __forceinline__ u16 bf16rn(float f) {
  u32 b = __float_as_uint(f);
  return (u16)((b + 0x7FFFu + ((b >> 16) & 1u)) >> 16);
}
__device__ __forceinline__ float bf16tof(u16 h) {
  return __uint_as_float(((u32)h) << 16);
}

// x fp32 -> bf16 hi/lo planes (contiguous, row-major); also zero the 2048 argmax slots.
__global__ void xconv_kernel(const float* __restrict__ x, char* __restrict__ xc,
                             u64* __restrict__ ws)
{
  int i = blockIdx.x * 256 + threadIdx.x;   // float4 id, BATCH*DIM/4 = 32768 total
  if (i < BATCH) ws[i] = 0;
  float4 v = ((const float4*)x)[i];
  float vv[4] = {v.x, v.y, v.z, v.w};
  short4v hv, lv;
#pragma unroll
  for (int k = 0; k < 4; ++k) {
    u16 hb = bf16rn(vv[k]);
    u16 lb = bf16rn(vv[k] - bf16tof(hb));
    hv[k] = (short)hb;
    lv[k] = (short)lb;
  }
  *(short4v*)(xc + (size_t)i * 8)       = hv;
  *(short4v*)(xc + XCP + (size_t)i * 8) = lv;
}

// sim = x . q^T via 3-pass bf16 hi/lo MFMA. A = q (32 cols/wave, persistent regs),
// B = x (bf16 planes, L2-hot, double-buffered register loads), no barriers in the
// K-loop. Each wave covers 32 q-cols x 1024 x-rows (m-half). One 12-MFMA chain per
// COMPUTE; 8192 waves total for latency hiding. Candidates: per-block LDS table
// (ds-atomics) -> coalesced dump to cand[block][1024]. Fallback: global atomicMax.
__global__ __launch_bounds__(256) void sim_kernel(
    const float* __restrict__ q, const char* __restrict__ xc,
    u64* __restrict__ ws, u64* __restrict__ cand)
{
  __shared__ u64 table[MROWS];   // 8 KB per-block candidate table

  const int tid  = threadIdx.x;
  const int lane = tid & 63;
  const int wave = tid >> 6;
  const int l31  = lane & 31;
  const int lh   = lane >> 5;

  const int gw       = blockIdx.x * 4 + wave;   // 0..8191
  const int colbase  = (gw & 4095) * 32;        // this wave's 32 q-columns
  const int mbase    = (gw >> 12) * MROWS;      // x-row half (block-uniform)

  if (cand) {
#pragma unroll
    for (int k = 0; k < 4; ++k) table[tid + k * 256] = 0;
    __syncthreads();
  }

  // ---- persistent A fragments from q (fp32 -> hi/lo in-register), A[m=l31][k=lh*8+j] ----
  short8 ah[4], al[4];
  {
    const float* qr = q + (size_t)(colbase + l31) * DIM + lh * 8;
#pragma unroll
    for (int kt = 0; kt < 4; ++kt) {
      float4 v0 = *(const float4*)(qr + kt * 16);
      float4 v1 = *(const float4*)(qr + kt * 16 + 4);
      float vv[8] = {v0.x, v0.y, v0.z, v0.w, v1.x, v1.y, v1.z, v1.w};
      short8 h, l;
#pragma unroll
      for (int i = 0; i < 8; ++i) {
        u16 hb = bf16rn(vv[i]);
        u16 lb = bf16rn(vv[i] - bf16tof(hb));
        h[i] = (short)hb;
        l[i] = (short)lb;
      }
      ah[kt] = h;
      al[kt] = l;
    }
  }

  // per-lane byte offset into an x plane for (row = mbase+m+l31, k-seg = kt*16+lh*8)
  const int lanoff = l31 * 128 + lh * 16;
  const int colb4  = colbase + 4 * lh;

  short8 b0h[4], b0l[4], b1h[4], b1l[4];

#define LOADB(BH, BL, M0)                                                   \
  {                                                                         \
    const char* ph = xc + (size_t)(mbase + (M0)) * 128 + lanoff;            \
    const char* pl = ph + XCP;                                              \
    _Pragma("unroll")                                                       \
    for (int kt = 0; kt < 4; ++kt) {                                        \
      BH[kt] = *(const short8*)(ph + kt * 32);                              \
      BL[kt] = *(const short8*)(pl + kt * 32);                              \
    }                                                                       \
  }

#define COMPUTE(BH, BL, M0)                                                 \
  {                                                                         \
    f32x16 acc;                                                             \
    _Pragma("unroll")                                                       \
    for (int i = 0; i < 16; ++i) acc[i] = 0.0f;                             \
    _Pragma("unroll")                                                       \
    for (int kt = 0; kt < 4; ++kt) {                                        \
      acc = __builtin_amdgcn_mfma_f32_32x32x16_bf16(ah[kt], BH[kt], acc, 0, 0, 0); \
      acc = __builtin_amdgcn_mfma_f32_32x32x16_bf16(al[kt], BH[kt], acc, 0, 0, 0); \
      acc = __builtin_amdgcn_mfma_f32_32x32x16_bf16(ah[kt], BL[kt], acc, 0, 0, 0); \
    }                                                                       \
    float bv = -3.0e38f;                                                    \
    u32   bc = 0;                                                           \
    /* q-col ascending in r; strict '>' -> smallest col on ties */          \
    _Pragma("unroll")                                                       \
    for (int r = 0; r < 16; ++r) {                                          \
      u32 c = (u32)(colb4 + (r & 3) + 8 * (r >> 2));                        \
      if (acc[r] > bv) { bv = acc[r]; bc = c; }                             \
    }                                                                       \
    u32 fb = __float_as_uint(bv);                                           \
    fb = (fb & 0x80000000u) ? ~fb : (fb | 0x80000000u);                     \
    u64 key = ((u64)fb << 32) | (u32)(~bc);                                 \
    u64 oth = __shfl_xor((unsigned long long)key, 32);                      \
    key = (oth > key) ? oth : key;   /* tie -> larger ~col = smaller col */ \
    if (lh == 0) {                                                          \
      if (cand) atomicMax(&table[(M0) + l31], key);                         \
      else      atomicMax(&ws[mbase + (M0) + l31], key);                    \
    }                                                                       \
  }

  LOADB(b0h, b0l, 0)
  for (int m0 = 0; m0 < MROWS; m0 += 64) {
    int n1 = m0 + 32;
    LOADB(b1h, b1l, n1)
    COMPUTE(b0h, b0l, m0)
    int n2 = (m0 + 64 < MROWS) ? m0 + 64 : 0;
    LOADB(b0h, b0l, n2)
    COMPUTE(b1h, b1l, n1)
  }
#undef LOADB
#undef COMPUTE

  if (cand) {
    __syncthreads();
    u64* dst = cand + (size_t)blockIdx.x * MROWS;
#pragma unroll
    for (int k = 0; k < 4; ++k) dst[tid + k * 256] = table[tid + k * 256];
  }
}

// Fused: new_queue copy-with-substitution (blocks 0..8191) + candidate reduce
// (blocks 8192..8319: 512 waves; wave = 64 rows x 64-block chunk, coalesced).
__global__ void finish_kernel(const float* __restrict__ x, const float* __restrict__ q,
                              const int* __restrict__ ptr_in,
                              const u64* __restrict__ cand,
                              u64* __restrict__ ws, float* __restrict__ newq)
{
  int bid = blockIdx.x;
  if (bid < 8192) {
    int i = bid * 256 + threadIdx.x;   // float4 index
    int r = i >> 4;
    int c = i & 15;
    int ptr = *ptr_in;
    u32 off = (u32)(r - ptr) & (QSIZE - 1);
    float4 v = (off < HALFB) ? ((const float4*)x)[off * 16 + c]
                             : ((const float4*)q)[i];
    ((float4*)newq)[i] = v;
  } else if (cand) {
    int w    = (bid - 8192) * 4 + (threadIdx.x >> 6);  // 0..511
    int lane = threadIdx.x & 63;
    int row  = (w & 31) * 64 + lane;                   // 0..2047
    int bb   = (row >> 10) * 1024 + (w >> 5) * 64;     // 64-block chunk in row's half
    u64 mx = 0;
#pragma unroll 8
    for (int b = bb; b < bb + 64; ++b) {
      u64 v = cand[(size_t)b * MROWS + (row & (MROWS - 1))];
      mx = (v > mx) ? v : mx;
    }
    atomicMax(&ws[row], mx);   // 16 atomics per slot, spread wide -> no contention
  }
}

__global__ void gather_kernel(const float* __restrict__ q,
                              const u64* __restrict__ ws,
                              const int* __restrict__ ptr_in,
                              float* __restrict__ nn,
                              float* __restrict__ nptr)
{
  int t = blockIdx.x * 256 + threadIdx.x;
  int b = t >> 6;
  int d = t & 63;
  u32 qidx = ~(u32)(ws[b]);
  nn[t] = q[(size_t)qidx * DIM + d];
  if (t == 0) *nptr = (float)(((*ptr_in) + HALFB) & (QSIZE - 1));
}

extern "C" void kernel_launch(void* const* d_in, const int* in_sizes, int n_in,
                              void* d_out, int out_size, void* d_ws, size_t ws_size,
                              hipStream_t stream)
{
  const float* x   = (const float*)d_in[0];
  const float* qx  = (const float*)d_in[1];
  const int*   ptr = (const int*)d_in[2];

  float* out  = (float*)d_out;
  float* nn   = out;
  float* newq = out + BATCH * DIM;
  float* nptr = out + BATCH * DIM + (size_t)QSIZE * DIM;

  // d_ws: [0,16K) argmax slots | [16K,528K) x bf16 planes | [528K,528K+16M) cand
  u64*  ws   = (u64*)d_ws;
  char* xc   = (char*)d_ws + WS_SLOTS;
  u64*  cand = (ws_size >= WS_NEED) ? (u64*)((char*)d_ws + WS_SLOTS + WS_XC) : nullptr;

  xconv_kernel<<<BATCH * DIM / 4 / 256, 256, 0, stream>>>(x, xc, ws);

  sim_kernel<<<NBLK, 256, 0, stream>>>(qx, xc, ws, cand);

  finish_kernel<<<8192 + (cand ? 128 : 0), 256, 0, stream>>>(
      x, qx, ptr, cand, ws, newq);

  gather_kernel<<<(BATCH * DIM) / 256, 256, 0, stream>>>(qx, ws, ptr, nn, nptr);
}

// Round 8
// 226.729 us; speedup vs baseline: 1.5191x; 1.5191x over previous
//
#include <hip/hip_runtime.h>

typedef unsigned long long u64;
typedef unsigned int u32;
typedef unsigned short u16;

#define BATCH 2048
#define DIM   64
#define QSIZE 131072
#define HALFB 1024

#define XCP (BATCH * DIM * 2)      // 256 KB: bytes per x bf16 plane (hi / lo)
#define NBLK 1024                  // sim blocks; 4 waves; wave = 64 q-cols x 1024 x-rows
#define MROWS 1024                 // x-rows per wave (half of BATCH)
#define WS_SLOTS 16384             // 2048 u64 argmax slots (fallback path)
#define WS_XC    (2 * XCP)         // 512 KB bf16 planes
#define WS_CAND  ((size_t)NBLK * MROWS * 8)   // 8 MB candidate buffer
#define WS_NEED  (WS_SLOTS + WS_XC + WS_CAND)

typedef __attribute__((ext_vector_type(8)))  short short8;
typedef __attribute__((ext_vector_type(4)))  short short4v;
typedef __attribute__((ext_vector_type(16))) float f32x16;

__device__ __forceinline__ u16 bf16rn(float f) {
  u32 b = __float_as_uint(f);
  return (u16)((b + 0x7FFFu + ((b >> 16) & 1u)) >> 16);
}
__device__ __forceinline__ float bf16tof(u16 h) {
  return __uint_as_float(((u32)h) << 16);
}

// x fp32 -> bf16 hi/lo planes (contiguous, row-major); also zero the 2048 argmax slots.
__global__ void xconv_kernel(const float* __restrict__ x, char* __restrict__ xc,
                             u64* __restrict__ ws)
{
  int i = blockIdx.x * 256 + threadIdx.x;   // float4 id, BATCH*DIM/4 = 32768 total
  if (i < BATCH) ws[i] = 0;
  float4 v = ((const float4*)x)[i];
  float vv[4] = {v.x, v.y, v.z, v.w};
  short4v hv, lv;
#pragma unroll
  for (int k = 0; k < 4; ++k) {
    u16 hb = bf16rn(vv[k]);
    u16 lb = bf16rn(vv[k] - bf16tof(hb));
    hv[k] = (short)hb;
    lv[k] = (short)lb;
  }
  *(short4v*)(xc + (size_t)i * 8)       = hv;
  *(short4v*)(xc + XCP + (size_t)i * 8) = lv;
}

// sim = x . q^T via 3-pass bf16 hi/lo MFMA. R6 per-wave shape (64 q-cols, two
// independent 12-MFMA chains per COMPUTE, ~112 VGPR) with the m-range split in
// half -> 4096 waves (2x R6's wave-level overlap). A = q persistent in regs;
// B = x bf16 planes (L2-hot), double-buffered register loads; no K-loop barriers.
// Candidates -> per-block LDS table (ds atomics) -> coalesced dump to cand.
__global__ __launch_bounds__(256) void sim_kernel(
    const float* __restrict__ q, const char* __restrict__ xc,
    u64* __restrict__ ws, u64* __restrict__ cand)
{
  __shared__ u64 table[MROWS];   // 8 KB per-block candidate table

  const int tid  = threadIdx.x;
  const int lane = tid & 63;
  const int wave = tid >> 6;
  const int l31  = lane & 31;
  const int lh   = lane >> 5;

  const int colbase = ((blockIdx.x & 511) * 4 + wave) * 64;  // wave's 64 q-columns
  const int mbase   = (blockIdx.x >> 9) * MROWS;             // x-row half (block-uniform)

  if (cand) {
#pragma unroll
    for (int k = 0; k < 4; ++k) table[tid + k * 256] = 0;
    __syncthreads();
  }

  // ---- persistent A fragments from q (fp32 -> hi/lo in-register), read once ----
  short8 ah[2][4], al[2][4];
#pragma unroll
  for (int ns = 0; ns < 2; ++ns) {
    const float* qr = q + (size_t)(colbase + ns * 32 + l31) * DIM + lh * 8;
#pragma unroll
    for (int kt = 0; kt < 4; ++kt) {
      float4 v0 = *(const float4*)(qr + kt * 16);
      float4 v1 = *(const float4*)(qr + kt * 16 + 4);
      float vv[8] = {v0.x, v0.y, v0.z, v0.w, v1.x, v1.y, v1.z, v1.w};
      short8 h, l;
#pragma unroll
      for (int i = 0; i < 8; ++i) {
        u16 hb = bf16rn(vv[i]);
        u16 lb = bf16rn(vv[i] - bf16tof(hb));
        h[i] = (short)hb;
        l[i] = (short)lb;
      }
      ah[ns][kt] = h;
      al[ns][kt] = l;
    }
  }

  // per-lane byte offset into an x plane for (row = mbase+m+l31, k-seg = kt*16+lh*8)
  const int lanoff = l31 * 128 + lh * 16;
  const int colb4  = colbase + 4 * lh;

  short8 b0h[4], b0l[4], b1h[4], b1l[4];

#define LOADB(BH, BL, M0)                                                   \
  {                                                                         \
    const char* ph = xc + (size_t)(mbase + (M0)) * 128 + lanoff;            \
    const char* pl = ph + XCP;                                              \
    _Pragma("unroll")                                                       \
    for (int kt = 0; kt < 4; ++kt) {                                        \
      BH[kt] = *(const short8*)(ph + kt * 32);                              \
      BL[kt] = *(const short8*)(pl + kt * 32);                              \
    }                                                                       \
  }

#define COMPUTE(BH, BL, M0)                                                 \
  {                                                                         \
    float bv = -3.0e38f;                                                    \
    u32   bc = 0;                                                           \
    _Pragma("unroll")                                                       \
    for (int ns = 0; ns < 2; ++ns) {                                        \
      f32x16 acc;                                                           \
      _Pragma("unroll")                                                     \
      for (int i = 0; i < 16; ++i) acc[i] = 0.0f;                           \
      _Pragma("unroll")                                                     \
      for (int kt = 0; kt < 4; ++kt) {                                      \
        acc = __builtin_amdgcn_mfma_f32_32x32x16_bf16(ah[ns][kt], BH[kt], acc, 0, 0, 0); \
        acc = __builtin_amdgcn_mfma_f32_32x32x16_bf16(al[ns][kt], BH[kt], acc, 0, 0, 0); \
        acc = __builtin_amdgcn_mfma_f32_32x32x16_bf16(ah[ns][kt], BL[kt], acc, 0, 0, 0); \
      }                                                                     \
      /* ascending q-col within lane; strict '>' -> smallest col on ties */ \
      _Pragma("unroll")                                                     \
      for (int r = 0; r < 16; ++r) {                                        \
        u32 c = (u32)(colb4 + ns * 32 + (r & 3) + 8 * (r >> 2));            \
        if (acc[r] > bv) { bv = acc[r]; bc = c; }                           \
      }                                                                     \
    }                                                                       \
    u32 fb = __float_as_uint(bv);                                           \
    fb = (fb & 0x80000000u) ? ~fb : (fb | 0x80000000u);                     \
    u64 key = ((u64)fb << 32) | (u32)(~bc);                                 \
    if (cand) atomicMax(&table[(M0) + l31], key);                           \
    else      atomicMax(&ws[mbase + (M0) + l31], key);                      \
  }

  LOADB(b0h, b0l, 0)
  for (int m0 = 0; m0 < MROWS; m0 += 64) {
    int n1 = m0 + 32;
    LOADB(b1h, b1l, n1)
    COMPUTE(b0h, b0l, m0)
    int n2 = (m0 + 64 < MROWS) ? m0 + 64 : 0;
    LOADB(b0h, b0l, n2)
    COMPUTE(b1h, b1l, n1)
  }
#undef LOADB
#undef COMPUTE

  if (cand) {
    __syncthreads();
    u64* dst = cand + (size_t)blockIdx.x * MROWS;
#pragma unroll
    for (int k = 0; k < 4; ++k) dst[tid + k * 256] = table[tid + k * 256];
  }
}

// Fused tail (main path): blocks 0..8191 produce new_queue; blocks 8192..8223
// each own 64 x-rows: reduce cand over that row-half's 512 sim-blocks (coalesced
// 512 B reads), combine via LDS, then gather nn for those rows. nptr by block 8192.
__global__ void tail_kernel(const float* __restrict__ x, const float* __restrict__ q,
                            const int* __restrict__ ptr_in,
                            const u64* __restrict__ cand,
                            float* __restrict__ newq, float* __restrict__ nn,
                            float* __restrict__ nptr)
{
  int bid = blockIdx.x;
  if (bid < 8192) {
    int i = bid * 256 + threadIdx.x;   // float4 index
    int r = i >> 4;
    int c = i & 15;
    int ptr = *ptr_in;
    u32 off = (u32)(r - ptr) & (QSIZE - 1);
    float4 v = (off < HALFB) ? ((const float4*)x)[off * 16 + c]
                             : ((const float4*)q)[i];
    ((float4*)newq)[i] = v;
    return;
  }

  __shared__ u64 tbl[64];
  int bid2 = bid - 8192;            // 0..31
  int tid  = threadIdx.x;
  int wv   = tid >> 6;              // 0..3: which 128-block chunk
  int ln   = tid & 63;
  int row  = bid2 * 64 + ln;        // global x-row handled by this lane
  int rowl = row & (MROWS - 1);
  int base = (row >> 10) * 512;     // row's m-half -> its 512 sim-blocks

  if (tid < 64) tbl[tid] = 0;
  __syncthreads();

  u64 mx = 0;
  int cb0 = base + wv * 128;
#pragma unroll 8
  for (int b = 0; b < 128; ++b) {
    u64 v = cand[(size_t)(cb0 + b) * MROWS + rowl];   // lanes: contiguous 512 B
    mx = (v > mx) ? v : mx;
  }
  atomicMax(&tbl[ln], mx);
  __syncthreads();

  // gather: 4 threads per row, 16 floats each
  int rl   = tid >> 2;
  int part = tid & 3;
  u32 qidx = ~(u32)(tbl[rl]);
  const float4* src = (const float4*)(q + (size_t)qidx * DIM) + part * 4;
  float4* dst = (float4*)(nn + (size_t)(bid2 * 64 + rl) * DIM) + part * 4;
#pragma unroll
  for (int k = 0; k < 4; ++k) dst[k] = src[k];

  if (bid2 == 0 && tid == 0) *nptr = (float)(((*ptr_in) + HALFB) & (QSIZE - 1));
}

// Fallback tail pieces (ws too small): R6-style separate kernels using ws slots.
__global__ void copy_update_kernel(const float* __restrict__ x,
                                   const float* __restrict__ q,
                                   const int* __restrict__ ptr_in,
                                   float* __restrict__ newq)
{
  int i = blockIdx.x * 256 + threadIdx.x;
  int r = i >> 4;
  int c = i & 15;
  int ptr = *ptr_in;
  u32 off = (u32)(r - ptr) & (QSIZE - 1);
  float4 v = (off < HALFB) ? ((const float4*)x)[off * 16 + c]
                           : ((const float4*)q)[i];
  ((float4*)newq)[i] = v;
}

__global__ void gather_kernel(const float* __restrict__ q,
                              const u64* __restrict__ ws,
                              const int* __restrict__ ptr_in,
                              float* __restrict__ nn,
                              float* __restrict__ nptr)
{
  int t = blockIdx.x * 256 + threadIdx.x;
  int b = t >> 6;
  int d = t & 63;
  u32 qidx = ~(u32)(ws[b]);
  nn[t] = q[(size_t)qidx * DIM + d];
  if (t == 0) *nptr = (float)(((*ptr_in) + HALFB) & (QSIZE - 1));
}

extern "C" void kernel_launch(void* const* d_in, const int* in_sizes, int n_in,
                              void* d_out, int out_size, void* d_ws, size_t ws_size,
                              hipStream_t stream)
{
  const float* x   = (const float*)d_in[0];
  const float* qx  = (const float*)d_in[1];
  const int*   ptr = (const int*)d_in[2];

  float* out  = (float*)d_out;
  float* nn   = out;
  float* newq = out + BATCH * DIM;
  float* nptr = out + BATCH * DIM + (size_t)QSIZE * DIM;

  // d_ws: [0,16K) argmax slots | [16K,528K) x bf16 planes | [528K,528K+8M) cand
  u64*  ws   = (u64*)d_ws;
  char* xc   = (char*)d_ws + WS_SLOTS;
  u64*  cand = (ws_size >= WS_NEED) ? (u64*)((char*)d_ws + WS_SLOTS + WS_XC) : nullptr;

  xconv_kernel<<<BATCH * DIM / 4 / 256, 256, 0, stream>>>(x, xc, ws);

  sim_kernel<<<NBLK, 256, 0, stream>>>(qx, xc, ws, cand);

  if (cand) {
    tail_kernel<<<8192 + 32, 256, 0, stream>>>(x, qx, ptr, cand, newq, nn, nptr);
  } else {
    copy_update_kernel<<<QSIZE * DIM / 4 / 256, 256, 0, stream>>>(x, qx, ptr, newq);
    gather_kernel<<<(BATCH * DIM) / 256, 256, 0, stream>>>(qx, ws, ptr, nn, nptr);
  }
}